// Round 13
// baseline (538.923 us; speedup 1.0000x reference)
//
#include <hip/hip_runtime.h>

typedef __attribute__((ext_vector_type(8))) short short8;
typedef __attribute__((ext_vector_type(4))) short sh4;
typedef __attribute__((ext_vector_type(4))) float f32x4;

#define BH 2097152   // B*H = 4096*512
#define NK 32

static __device__ __forceinline__ short f2bf(float f) {
  union { float f; unsigned int u; } c; c.f = f;
  unsigned int u = c.u + 0x7FFFu + ((c.u >> 16) & 1u);
  return (short)(u >> 16);
}
static __device__ __forceinline__ float bf2f(short s) {
  union { unsigned int u; float f; } c;
  c.u = ((unsigned int)(unsigned short)s) << 16;
  return c.f;
}
static __device__ __forceinline__ float ntloadf(const float* p) {
  return __builtin_nontemporal_load(p);
}
static __device__ __forceinline__ void ntstoref(float* p, float v) {
  __builtin_nontemporal_store(v, p);
}
static __device__ __forceinline__ f32x4 ntload4(const float* p) {
  return __builtin_nontemporal_load((const f32x4*)p);
}
static __device__ __forceinline__ void ntstore4(float* p, f32x4 v) {
  __builtin_nontemporal_store(v, (f32x4*)p);
}

// ---------------- ws layout (shorts) ----------------
#define WS_XH     0          // [4096][1024] bf16 concat(sample,hidden)
#define WS_MEMPB  4194304    // [4096][512]
#define WS_WI     6291456    // [512][1024]
#define WS_WO     6815744
#define WS_WC     7340032
#define WS_WM     7864320    // [512][1536]
#define WS_WOUT   8650752    // [512][512]
#define WS_HIDB   8912896    // [4096][512] bf16 hidden_new
#define WS_IGB    11010048   // (unused in mega path)
#define WS_OGB    13107200
#define WS_CGB    15204352
#define WS_END    17301504
#define FAST_NEED_BYTES ((size_t)WS_END * 2)

// ============================ FAST PATH ============================

__global__ __launch_bounds__(256) void prep(
    const float* __restrict__ sample, const float* __restrict__ hidden,
    const float* __restrict__ memp,
    const float* __restrict__ wi, const float* __restrict__ wo,
    const float* __restrict__ wc, const float* __restrict__ wm,
    const float* __restrict__ wout, short* __restrict__ ws) {
  const size_t v = ((size_t)blockIdx.x * 256 + threadIdx.x) * 4;
  const float* src;
  short* dst;
  if (v < 2097152) {                     // sample -> xh[:, :512]
    const size_t r = v >> 9, c = v & 511;
    src = sample + v; dst = ws + WS_XH + r * 1024 + c;
  } else if (v < 4194304) {              // hidden -> xh[:, 512:]
    const size_t u = v - 2097152, r = u >> 9, c = u & 511;
    src = hidden + u; dst = ws + WS_XH + r * 1024 + 512 + c;
  } else if (v < 6291456) {              // memp
    const size_t u = v - 4194304; src = memp + u; dst = ws + WS_MEMPB + u;
  } else if (v < 6815744) {
    const size_t u = v - 6291456; src = wi + u; dst = ws + WS_WI + u;
  } else if (v < 7340032) {
    const size_t u = v - 6815744; src = wo + u; dst = ws + WS_WO + u;
  } else if (v < 7864320) {
    const size_t u = v - 7340032; src = wc + u; dst = ws + WS_WC + u;
  } else if (v < 8650752) {
    const size_t u = v - 7864320; src = wm + u; dst = ws + WS_WM + u;
  } else {                               // wout, ends at 8912896
    const size_t u = v - 8650752; src = wout + u; dst = ws + WS_WOUT + u;
  }
  const f32x4 x = *(const f32x4*)src;
  sh4 s;
#pragma unroll
  for (int j = 0; j < 4; ++j) s[j] = f2bf(x[j]);
  *(sh4*)dst = s;
}

struct FastArgs {
  const short *xh, *mempb, *hidb;
  const short *W[5];
  const float *bia[5];
  float *memo, *out0; // f32 outputs
};

// m-gate (mode 2, K=1536) and out GEMM (mode 1, K=512): 64x64 tile, BK=64,
// double-buffered LDS (r12 structure, verified). Grid (64, 8).
__global__ __launch_bounds__(256) void gemm_fast(FastArgs a, int mode) {
  __shared__ short lA[2][64 * 64];
  __shared__ short lB[2][64 * 64];
  const int t = threadIdx.x;
  const int lane = t & 63;
  const int wv = t >> 6;
  const int mt = blockIdx.x;
  const int gate = (mode == 2) ? 3 : 4;
  const int nsub = blockIdx.y;
  const short* W = a.W[gate];
  const int Klen = (gate == 3) ? 1536 : 512;
  const int m0 = mt * 64;
  const int n0 = nsub * 64;

  f32x4 acc[2][2];
  const f32x4 z = {0.f, 0.f, 0.f, 0.f};
#pragma unroll
  for (int i = 0; i < 2; ++i)
#pragma unroll
    for (int j = 0; j < 2; ++j) acc[i][j] = z;

  const int wr = wv >> 1, wc2 = wv & 1;

  auto stage = [&](int buf, int kt) {
    const int kb = kt << 6;
#pragma unroll
    for (int it = 0; it < 2; ++it) {
      const int chunk = it * 256 + t;
      const int row = chunk >> 3;
      const int kk = (chunk & 7) << 3;
      const int gk = kb + kk;
      const short* src;
      if (gate == 4)       src = a.hidb  + (size_t)(m0 + row) * 512 + gk;
      else if (gk < 1024)  src = a.xh    + (size_t)(m0 + row) * 1024 + gk;
      else                 src = a.mempb + (size_t)(m0 + row) * 512 + (gk - 1024);
      __builtin_amdgcn_global_load_lds(
          (const __attribute__((address_space(1))) void*)src,
          (__attribute__((address_space(3))) void*)(&lA[buf][0] + (size_t)(it * 256 + wv * 64) * 8),
          16, 0, 0);
    }
#pragma unroll
    for (int it = 0; it < 2; ++it) {
      const int chunk = it * 256 + t;
      const int row = chunk >> 3;
      const int kk = (chunk & 7) << 3;
      const short* src = W + (size_t)(n0 + row) * Klen + kb + kk;
      __builtin_amdgcn_global_load_lds(
          (const __attribute__((address_space(1))) void*)src,
          (__attribute__((address_space(3))) void*)(&lB[buf][0] + (size_t)(it * 256 + wv * 64) * 8),
          16, 0, 0);
    }
  };

  const int Ktiles = Klen >> 6;
  stage(0, 0);
  __syncthreads();
  int cur = 0;
  for (int kt = 0; kt < Ktiles; ++kt) {
    if (kt + 1 < Ktiles) stage(cur ^ 1, kt + 1);
#pragma unroll
    for (int ks = 0; ks < 2; ++ks) {
      short8 av[2], bv[2];
#pragma unroll
      for (int mi = 0; mi < 2; ++mi)
        av[mi] = *(const short8*)(&lA[cur][0] + (wr * 32 + mi * 16 + (lane & 15)) * 64 + ks * 32 + ((lane >> 4) << 3));
#pragma unroll
      for (int ni = 0; ni < 2; ++ni)
        bv[ni] = *(const short8*)(&lB[cur][0] + (wc2 * 32 + ni * 16 + (lane & 15)) * 64 + ks * 32 + ((lane >> 4) << 3));
#pragma unroll
      for (int mi = 0; mi < 2; ++mi)
#pragma unroll
        for (int ni = 0; ni < 2; ++ni)
          acc[mi][ni] = __builtin_amdgcn_mfma_f32_16x16x32_bf16(av[mi], bv[ni], acc[mi][ni], 0, 0, 0);
    }
    __syncthreads();
    cur ^= 1;
  }

  const float* bias = a.bia[gate];
  const int rg = lane >> 4;
  const int ci = lane & 15;
#pragma unroll
  for (int mi = 0; mi < 2; ++mi) {
#pragma unroll
    for (int ni = 0; ni < 2; ++ni) {
      const int col = n0 + wc2 * 32 + ni * 16 + ci;
      const float bvl = bias[col];
#pragma unroll
      for (int r = 0; r < 4; ++r) {
        const int row = m0 + wr * 32 + mi * 16 + rg * 4 + r;
        const float v = acc[mi][ni][r] + bvl;
        const size_t o = (size_t)row * 512 + col;
        if (gate == 3) a.memo[o] = 0.5f / (1.f + __expf(-v));
        else           a.out0[o] = v;
      }
    }
  }
}

// MEGA: per 64x64 output patch: G = i/o/c GEMMs (gates stay in registers),
// S = cell shift-copy + cumprod filter for the same cells, F = cell_new /
// hidden epilogue. Phase parity: even blocks G->S, odd blocks S->G, so ~half
// the resident blocks stream (HBM) while half do MFMA -- overlap inside one
// resource envelope. S depends only on memo (m-gate dispatch).
__global__ __launch_bounds__(256) void mega(
    FastArgs a, const float* __restrict__ cell, const float* __restrict__ mem,
    float* __restrict__ upd, float* __restrict__ hid, short* __restrict__ hidb)
{
  __shared__ short lA[2][64 * 64];
  __shared__ short lB[2][64 * 64];
  const int t = threadIdx.x;
  const int lane = t & 63;
  const int wv = t >> 6;
  const int mt = blockIdx.x;
  const int nsub = blockIdx.y;
  const int m0 = mt * 64;
  const int n0 = nsub * 64;
  const int wr = wv >> 1, wc2 = wv & 1;
  const int rg = lane >> 4, ci = lane & 15;

  float g3[3][2][2][4];     // i, o, c gate values (post-activation, f32)
  float ac[2][2][4];        // filter accumulator
  unsigned idxv[2][2][4];   // this thread's 16 cell indices
#pragma unroll
  for (int mi = 0; mi < 2; ++mi)
#pragma unroll
    for (int ni = 0; ni < 2; ++ni)
#pragma unroll
      for (int r = 0; r < 4; ++r) {
        const int row = m0 + wr * 32 + mi * 16 + rg * 4 + r;
        const int col = n0 + wc2 * 32 + ni * 16 + ci;
        idxv[mi][ni][r] = (unsigned)(row * 512 + col);
      }

  // ---- G: three K=1024 GEMMs (A = xh), gates -> registers ----
  auto phaseG = [&]() {
#pragma unroll
    for (int g = 0; g < 3; ++g) {
      const short* W = a.W[g];
      f32x4 acc[2][2];
      const f32x4 z = {0.f, 0.f, 0.f, 0.f};
#pragma unroll
      for (int i = 0; i < 2; ++i)
#pragma unroll
        for (int j = 0; j < 2; ++j) acc[i][j] = z;

      auto stage = [&](int buf, int kt) {
        const int kb = kt << 6;
#pragma unroll
        for (int it = 0; it < 2; ++it) {
          const int chunk = it * 256 + t;
          const int row = chunk >> 3;
          const int kk = (chunk & 7) << 3;
          const short* src = a.xh + (size_t)(m0 + row) * 1024 + kb + kk;
          __builtin_amdgcn_global_load_lds(
              (const __attribute__((address_space(1))) void*)src,
              (__attribute__((address_space(3))) void*)(&lA[buf][0] + (size_t)(it * 256 + wv * 64) * 8),
              16, 0, 0);
        }
#pragma unroll
        for (int it = 0; it < 2; ++it) {
          const int chunk = it * 256 + t;
          const int row = chunk >> 3;
          const int kk = (chunk & 7) << 3;
          const short* src = W + (size_t)(n0 + row) * 1024 + kb + kk;
          __builtin_amdgcn_global_load_lds(
              (const __attribute__((address_space(1))) void*)src,
              (__attribute__((address_space(3))) void*)(&lB[buf][0] + (size_t)(it * 256 + wv * 64) * 8),
              16, 0, 0);
        }
      };

      stage(0, 0);
      __syncthreads();
      int cur = 0;
      for (int kt = 0; kt < 16; ++kt) {
        if (kt + 1 < 16) stage(cur ^ 1, kt + 1);
#pragma unroll
        for (int ks = 0; ks < 2; ++ks) {
          short8 av[2], bv[2];
#pragma unroll
          for (int mi = 0; mi < 2; ++mi)
            av[mi] = *(const short8*)(&lA[cur][0] + (wr * 32 + mi * 16 + (lane & 15)) * 64 + ks * 32 + ((lane >> 4) << 3));
#pragma unroll
          for (int ni = 0; ni < 2; ++ni)
            bv[ni] = *(const short8*)(&lB[cur][0] + (wc2 * 32 + ni * 16 + (lane & 15)) * 64 + ks * 32 + ((lane >> 4) << 3));
#pragma unroll
          for (int mi = 0; mi < 2; ++mi)
#pragma unroll
            for (int ni = 0; ni < 2; ++ni)
              acc[mi][ni] = __builtin_amdgcn_mfma_f32_16x16x32_bf16(av[mi], bv[ni], acc[mi][ni], 0, 0, 0);
        }
        __syncthreads();
        cur ^= 1;
      }

      const float* bias = a.bia[g];
#pragma unroll
      for (int mi = 0; mi < 2; ++mi)
#pragma unroll
        for (int ni = 0; ni < 2; ++ni) {
          const int col = n0 + wc2 * 32 + ni * 16 + ci;
          const float bvl = bias[col];
#pragma unroll
          for (int r = 0; r < 4; ++r) {
            const float v = acc[mi][ni][r] + bvl;
            if (g == 2) g3[2][mi][ni][r] = 1.f - 2.f / (1.f + __expf(2.f * v));   // tanh
            else        g3[g][mi][ni][r] = 1.f / (1.f + __expf(-v));              // sigmoid
          }
        }
    }
  };

  // ---- S: shift-copy + cumprod filter over this thread's 16 cells ----
  auto phaseS = [&]() {
    float d[2][2][4], pp[2][2][4];
#pragma unroll
    for (int mi = 0; mi < 2; ++mi)
#pragma unroll
      for (int ni = 0; ni < 2; ++ni)
#pragma unroll
        for (int r = 0; r < 4; ++r) {
          d[mi][ni][r] = mem[idxv[mi][ni][r]];
          pp[mi][ni][r] = 1.f;
          ac[mi][ni][r] = 0.f;
        }
#pragma unroll
    for (int i2 = 0; i2 < 32; ++i2) {
      const int k = 31 - i2;
      const float inv = 1.f / (float)(i2 + 1);
      const float* cp = cell + (size_t)k * BH;
      float* up = upd + (size_t)(k - 1) * BH;
#pragma unroll
      for (int mi = 0; mi < 2; ++mi)
#pragma unroll
        for (int ni = 0; ni < 2; ++ni)
#pragma unroll
          for (int r = 0; r < 4; ++r) {
            const unsigned ix = idxv[mi][ni][r];
            const float cv = ntloadf(cp + ix);
            pp[mi][ni][r] *= ((float)i2 - d[mi][ni][r]) * inv;
            ac[mi][ni][r] += cv * pp[mi][ni][r];
            if (k >= 1) ntstoref(up + ix, cv);
          }
    }
  };

  const int par = (mt + nsub) & 1;
  if (par == 0) { phaseG(); phaseS(); }
  else          { phaseS(); phaseG(); }

  // ---- F: cell_new, hidden ----
  float* up31 = upd + (size_t)31 * BH;
#pragma unroll
  for (int mi = 0; mi < 2; ++mi)
#pragma unroll
    for (int ni = 0; ni < 2; ++ni)
#pragma unroll
      for (int r = 0; r < 4; ++r) {
        const unsigned ix = idxv[mi][ni][r];
        const float cn = -ac[mi][ni][r] + g3[2][mi][ni][r] * g3[0][mi][ni][r];
        ntstoref(up31 + ix, cn);
        const float th = 1.f - 2.f / (1.f + __expf(2.f * cn));
        const float h = g3[1][mi][ni][r] * th;
        hid[ix] = h;
        hidb[ix] = f2bf(h);
      }
}

// ============================ FALLBACK (round-3, passed) ============================

struct GemmArgs {
  const float *sample, *hidden, *memp, *hid_in;
  const float *W[5];
  const float *bia[5];
  float *dst[5];
};

__global__ __launch_bounds__(256) void gemm_all(GemmArgs g, int mode) {
  __shared__ short lA[128 * 64];
  __shared__ short lB[128 * 64];
  const int t = threadIdx.x;
  const int lane = t & 63;
  const int mt = blockIdx.x;
  int gate, nsub;
  if (mode == 0) { gate = blockIdx.y >> 2; nsub = blockIdx.y & 3; }
  else           { gate = 4;               nsub = blockIdx.y; }
  const float* W = g.W[gate];
  const float* bias = g.bia[gate];
  float* dst = g.dst[gate];
  const int Klen = (gate == 3) ? 1536 : (gate == 4 ? 512 : 1024);
  const int m0 = mt * 128;
  const int n0 = nsub * 128;

  f32x4 acc[4][4];
  const f32x4 z = {0.f, 0.f, 0.f, 0.f};
#pragma unroll
  for (int i = 0; i < 4; ++i)
#pragma unroll
    for (int j = 0; j < 4; ++j) acc[i][j] = z;

  const int wv = t >> 6;
  const int wr = wv >> 1, wc = wv & 1;
  const int Ktiles = Klen >> 6;
  for (int kt = 0; kt < Ktiles; ++kt) {
    const int kb = kt << 6;
#pragma unroll
    for (int it = 0; it < 4; ++it) {
      const int chunk = it * 256 + t;
      const int row = chunk >> 3;
      const int kk = (chunk & 7) << 3;
      const int gk = kb + kk;
      const float* src;
      if (mode == 1)      src = g.hid_in + (size_t)(m0 + row) * 512 + gk;
      else if (gk < 512)  src = g.sample + (size_t)(m0 + row) * 512 + gk;
      else if (gk < 1024) src = g.hidden + (size_t)(m0 + row) * 512 + (gk - 512);
      else                src = g.memp   + (size_t)(m0 + row) * 512 + (gk - 1024);
      const f32x4 v0 = *(const f32x4*)src;
      const f32x4 v1 = *(const f32x4*)(src + 4);
      short8 s;
#pragma unroll
      for (int j = 0; j < 4; ++j) { s[j] = f2bf(v0[j]); s[4 + j] = f2bf(v1[j]); }
      *(short8*)(lA + row * 64 + kk) = s;
    }
#pragma unroll
    for (int it = 0; it < 4; ++it) {
      const int chunk = it * 256 + t;
      const int row = chunk >> 3;
      const int kk = (chunk & 7) << 3;
      const float* src = W + (size_t)(n0 + row) * Klen + kb + kk;
      const f32x4 v0 = *(const f32x4*)src;
      const f32x4 v1 = *(const f32x4*)(src + 4);
      short8 s;
#pragma unroll
      for (int j = 0; j < 4; ++j) { s[j] = f2bf(v0[j]); s[4 + j] = f2bf(v1[j]); }
      *(short8*)(lB + row * 64 + kk) = s;
    }
    __syncthreads();
#pragma unroll
    for (int ks = 0; ks < 2; ++ks) {
      short8 av[4], bv[4];
#pragma unroll
      for (int mi = 0; mi < 4; ++mi)
        av[mi] = *(const short8*)(lA + (wr * 64 + mi * 16 + (lane & 15)) * 64 + ks * 32 + ((lane >> 4) << 3));
#pragma unroll
      for (int ni = 0; ni < 4; ++ni)
        bv[ni] = *(const short8*)(lB + (wc * 64 + ni * 16 + (lane & 15)) * 64 + ks * 32 + ((lane >> 4) << 3));
#pragma unroll
      for (int mi = 0; mi < 4; ++mi)
#pragma unroll
        for (int ni = 0; ni < 4; ++ni)
          acc[mi][ni] = __builtin_amdgcn_mfma_f32_16x16x32_bf16(av[mi], bv[ni], acc[mi][ni], 0, 0, 0);
    }
    __syncthreads();
  }

  const int rg = lane >> 4;
  const int ci = lane & 15;
#pragma unroll
  for (int mi = 0; mi < 4; ++mi) {
#pragma unroll
    for (int ni = 0; ni < 4; ++ni) {
      const int col = n0 + wc * 64 + ni * 16 + ci;
      const float bvl = bias[col];
#pragma unroll
      for (int r = 0; r < 4; ++r) {
        const int row = m0 + wr * 64 + mi * 16 + rg * 4 + r;
        const float v = acc[mi][ni][r] + bvl;
        float o;
        if (gate == 0 || gate == 1)  o = 1.f / (1.f + __expf(-v));
        else if (gate == 2)          o = 1.f - 2.f / (1.f + __expf(2.f * v));
        else if (gate == 3)          o = 0.5f / (1.f + __expf(-v));
        else                         o = v;
        dst[(size_t)row * 512 + col] = o;
      }
    }
  }
}

__global__ __launch_bounds__(256) void cell_update(
    const float* __restrict__ cell, const float* ig, const float* og, const float* cg,
    const float* mem, float* upd, float* __restrict__ hid)
{
  const size_t idx = ((size_t)blockIdx.x * 256 + threadIdx.x) * 4;
  const f32x4 dv = *(const f32x4*)(mem + idx);
  const f32x4 iv = *(const f32x4*)(ig + idx);
  const f32x4 ov = *(const f32x4*)(og + idx);
  const f32x4 gv = *(const f32x4*)(cg + idx);
  asm volatile("" ::: "memory");
  float p[4], acc[4];
#pragma unroll
  for (int j = 0; j < 4; ++j) { p[j] = 1.f; acc[j] = 0.f; }
#pragma unroll
  for (int i = 0; i < 32; ++i) {
    const int k = 31 - i;
    const f32x4 c = *(const f32x4*)(cell + (size_t)k * BH + idx);
    const float inv = 1.f / (float)(i + 1);
#pragma unroll
    for (int j = 0; j < 4; ++j) {
      p[j] *= ((float)i - dv[j]) * inv;
      acc[j] += c[j] * p[j];
    }
    if (k >= 1) *(f32x4*)(upd + (size_t)(k - 1) * BH + idx) = c;
  }
  f32x4 cno, ho;
#pragma unroll
  for (int j = 0; j < 4; ++j) {
    const float cn = -acc[j] + gv[j] * iv[j];
    cno[j] = cn;
    const float th = 1.f - 2.f / (1.f + __expf(2.f * cn));
    ho[j] = ov[j] * th;
  }
  *(f32x4*)(upd + (size_t)31 * BH + idx) = cno;
  *(f32x4*)(hid + idx) = ho;
}

// ============================ launch ============================

extern "C" void kernel_launch(void* const* d_in, const int* in_sizes, int n_in,
                              void* d_out, int out_size, void* d_ws, size_t ws_size,
                              hipStream_t stream) {
  const float* sample = (const float*)d_in[0];
  const float* hidden = (const float*)d_in[1];
  const float* cell   = (const float*)d_in[2];
  const float* memp   = (const float*)d_in[3];

  float* out0 = (float*)d_out;                 // [B,O]   output
  float* hid  = out0 + (size_t)BH;             // [B,H]   hidden_new
  float* upd  = hid + (size_t)BH;              // [K,B,H] updated_cell_states
  float* memo = upd + (size_t)NK * BH;         // [B,H]   mem_new

  if (ws_size >= FAST_NEED_BYTES) {
    short* ws = (short*)d_ws;
    hipLaunchKernelGGL(prep, dim3(8704), dim3(256), 0, stream,
                       sample, hidden, memp,
                       (const float*)d_in[4], (const float*)d_in[6],
                       (const float*)d_in[10], (const float*)d_in[8],
                       (const float*)d_in[12], ws);
    FastArgs a;
    a.xh = ws + WS_XH; a.mempb = ws + WS_MEMPB; a.hidb = ws + WS_HIDB;
    a.W[0] = ws + WS_WI; a.W[1] = ws + WS_WO; a.W[2] = ws + WS_WC;
    a.W[3] = ws + WS_WM; a.W[4] = ws + WS_WOUT;
    a.bia[0] = (const float*)d_in[5];  a.bia[1] = (const float*)d_in[7];
    a.bia[2] = (const float*)d_in[11]; a.bia[3] = (const float*)d_in[9];
    a.bia[4] = (const float*)d_in[13];
    a.memo = memo; a.out0 = out0;

    // 1) m-gate -> mem_new
    hipLaunchKernelGGL(gemm_fast, dim3(64, 8), dim3(256), 0, stream, a, 2);
    // 2) mega: i/o/c GEMMs + cell stream + epilogue, phase-parity overlapped
    hipLaunchKernelGGL(mega, dim3(64, 8), dim3(256), 0, stream,
                       a, cell, (const float*)memo, upd, hid, ws + WS_HIDB);
    // 3) out GEMM
    hipLaunchKernelGGL(gemm_fast, dim3(64, 8), dim3(256), 0, stream, a, 1);
    return;
  }

  // fallback: round-3 path (passed)
  float* ig;
  float* og;
  float* cg;
  if (ws_size >= (size_t)3 * BH * sizeof(float)) {
    ig = (float*)d_ws; og = ig + (size_t)BH; cg = og + (size_t)BH;
  } else {
    ig = upd; og = upd + (size_t)BH; cg = upd + 2 * (size_t)BH;
  }
  GemmArgs g;
  g.sample = sample; g.hidden = hidden; g.memp = memp; g.hid_in = hid;
  g.W[0] = (const float*)d_in[4];  g.bia[0] = (const float*)d_in[5];
  g.W[1] = (const float*)d_in[6];  g.bia[1] = (const float*)d_in[7];
  g.W[3] = (const float*)d_in[8];  g.bia[3] = (const float*)d_in[9];
  g.W[2] = (const float*)d_in[10]; g.bia[2] = (const float*)d_in[11];
  g.W[4] = (const float*)d_in[12]; g.bia[4] = (const float*)d_in[13];
  g.dst[0] = ig; g.dst[1] = og; g.dst[2] = cg; g.dst[3] = memo; g.dst[4] = out0;

  hipLaunchKernelGGL(gemm_all, dim3(32, 16), dim3(256), 0, stream, g, 0);
  hipLaunchKernelGGL(cell_update, dim3(2048), dim3(256), 0, stream,
                     cell, (const float*)ig, (const float*)og, (const float*)cg,
                     (const float*)memo, upd, hid);
  hipLaunchKernelGGL(gemm_all, dim3(32, 4), dim3(256), 0, stream, g, 1);
}

// Round 14
// 170.436 us; speedup vs baseline: 3.1620x; 3.1620x over previous
//
#include <hip/hip_runtime.h>

typedef __attribute__((ext_vector_type(8))) short short8;
typedef __attribute__((ext_vector_type(4))) short sh4;
typedef __attribute__((ext_vector_type(4))) float f32x4;

#define BH 2097152   // B*H = 4096*512
#define NK 32

// f32 -> bf16 round-to-nearest-even
static __device__ __forceinline__ short f2bf(float f) {
  union { float f; unsigned int u; } c; c.f = f;
  unsigned int u = c.u + 0x7FFFu + ((c.u >> 16) & 1u);
  return (short)(u >> 16);
}
static __device__ __forceinline__ float bf2f(short s) {
  union { unsigned int u; float f; } c;
  c.u = ((unsigned int)(unsigned short)s) << 16;
  return c.f;
}
static __device__ __forceinline__ f32x4 ntload(const float* p) {
  return __builtin_nontemporal_load((const f32x4*)p);
}
static __device__ __forceinline__ void ntstore(float* p, f32x4 v) {
  __builtin_nontemporal_store(v, (f32x4*)p);
}

// ---------------- ws layout (shorts) ----------------
#define WS_XH     0          // [4096][1024] bf16 concat(sample,hidden)
#define WS_MEMPB  4194304    // [4096][512]
#define WS_WI     6291456    // [512][1024]
#define WS_WO     6815744
#define WS_WC     7340032
#define WS_WM     7864320    // [512][1536]
#define WS_WOUT   8650752    // [512][512]
#define WS_HIDB   8912896    // [4096][512] bf16 hidden_new
#define WS_IGB    11010048   // [4096][512] bf16 gates
#define WS_OGB    13107200
#define WS_CGB    15204352
#define WS_END    17301504
#define FAST_NEED_BYTES ((size_t)WS_END * 2)

// ============================ FAST PATH ============================

__global__ __launch_bounds__(256) void prep(
    const float* __restrict__ sample, const float* __restrict__ hidden,
    const float* __restrict__ memp,
    const float* __restrict__ wi, const float* __restrict__ wo,
    const float* __restrict__ wc, const float* __restrict__ wm,
    const float* __restrict__ wout, short* __restrict__ ws) {
  const size_t v = ((size_t)blockIdx.x * 256 + threadIdx.x) * 4;
  const float* src;
  short* dst;
  if (v < 2097152) {                     // sample -> xh[:, :512]
    const size_t r = v >> 9, c = v & 511;
    src = sample + v; dst = ws + WS_XH + r * 1024 + c;
  } else if (v < 4194304) {              // hidden -> xh[:, 512:]
    const size_t u = v - 2097152, r = u >> 9, c = u & 511;
    src = hidden + u; dst = ws + WS_XH + r * 1024 + 512 + c;
  } else if (v < 6291456) {              // memp
    const size_t u = v - 4194304; src = memp + u; dst = ws + WS_MEMPB + u;
  } else if (v < 6815744) {
    const size_t u = v - 6291456; src = wi + u; dst = ws + WS_WI + u;
  } else if (v < 7340032) {
    const size_t u = v - 6815744; src = wo + u; dst = ws + WS_WO + u;
  } else if (v < 7864320) {
    const size_t u = v - 7340032; src = wc + u; dst = ws + WS_WC + u;
  } else if (v < 8650752) {
    const size_t u = v - 7864320; src = wm + u; dst = ws + WS_WM + u;
  } else {                               // wout, ends at 8912896
    const size_t u = v - 8650752; src = wout + u; dst = ws + WS_WOUT + u;
  }
  const f32x4 x = *(const f32x4*)src;
  sh4 s;
#pragma unroll
  for (int j = 0; j < 4; ++j) s[j] = f2bf(x[j]);
  *(sh4*)dst = s;
}

struct FastArgs {
  const short *xh, *mempb, *hidb;
  const short *W[5];
  const float *bia[5];
  short *gdst[3];     // igb, ogb, cgb (bf16)
  float *memo, *out0; // f32 outputs
};

// bf16 GEMM, 64x64 tile, BK=64, double-buffered LDS (r12 structure, 185.4us).
// mode0: gate via gmap {m,i,o,c} of y>>3; nsub=y&7.  mode1: gate4 out GEMM.
__global__ __launch_bounds__(256) void gemm_fast(FastArgs a, int mode) {
  __shared__ short lA[2][64 * 64];
  __shared__ short lB[2][64 * 64];
  const int t = threadIdx.x;
  const int lane = t & 63;
  const int wv = t >> 6;
  const int mt = blockIdx.x;
  int gate, nsub;
  if (mode == 0) {
    const int gmap[4] = {3, 0, 1, 2};   // m first (longest K)
    gate = gmap[blockIdx.y >> 3]; nsub = blockIdx.y & 7;
  } else { gate = 4; nsub = blockIdx.y; }
  const short* W = a.W[gate];
  const int Klen = (gate == 3) ? 1536 : (gate == 4 ? 512 : 1024);
  const int m0 = mt * 64;
  const int n0 = nsub * 64;

  f32x4 acc[2][2];
  const f32x4 z = {0.f, 0.f, 0.f, 0.f};
#pragma unroll
  for (int i = 0; i < 2; ++i)
#pragma unroll
    for (int j = 0; j < 2; ++j) acc[i][j] = z;

  const int wr = wv >> 1, wc2 = wv & 1;   // wave sub-tile: 32 x 32

  auto stage = [&](int buf, int kt) {
    const int kb = kt << 6;
#pragma unroll
    for (int it = 0; it < 2; ++it) {
      const int chunk = it * 256 + t;
      const int row = chunk >> 3;          // 0..63
      const int kk = (chunk & 7) << 3;     // 0..56
      const int gk = kb + kk;
      const short* src;
      if (gate == 4)                    src = a.hidb  + (size_t)(m0 + row) * 512 + gk;
      else if (gate != 3 || gk < 1024)  src = a.xh    + (size_t)(m0 + row) * 1024 + gk;
      else                              src = a.mempb + (size_t)(m0 + row) * 512 + (gk - 1024);
      __builtin_amdgcn_global_load_lds(
          (const __attribute__((address_space(1))) void*)src,
          (__attribute__((address_space(3))) void*)(&lA[buf][0] + (size_t)(it * 256 + wv * 64) * 8),
          16, 0, 0);
    }
#pragma unroll
    for (int it = 0; it < 2; ++it) {
      const int chunk = it * 256 + t;
      const int row = chunk >> 3;
      const int kk = (chunk & 7) << 3;
      const short* src = W + (size_t)(n0 + row) * Klen + kb + kk;
      __builtin_amdgcn_global_load_lds(
          (const __attribute__((address_space(1))) void*)src,
          (__attribute__((address_space(3))) void*)(&lB[buf][0] + (size_t)(it * 256 + wv * 64) * 8),
          16, 0, 0);
    }
  };

  const int Ktiles = Klen >> 6;
  stage(0, 0);
  __syncthreads();          // drains vmcnt(0): buf0 ready
  int cur = 0;
  for (int kt = 0; kt < Ktiles; ++kt) {
    if (kt + 1 < Ktiles) stage(cur ^ 1, kt + 1);   // prefetch overlaps compute
#pragma unroll
    for (int ks = 0; ks < 2; ++ks) {
      short8 av[2], bv[2];
#pragma unroll
      for (int mi = 0; mi < 2; ++mi)
        av[mi] = *(const short8*)(&lA[cur][0] + (wr * 32 + mi * 16 + (lane & 15)) * 64 + ks * 32 + ((lane >> 4) << 3));
#pragma unroll
      for (int ni = 0; ni < 2; ++ni)
        bv[ni] = *(const short8*)(&lB[cur][0] + (wc2 * 32 + ni * 16 + (lane & 15)) * 64 + ks * 32 + ((lane >> 4) << 3));
#pragma unroll
      for (int mi = 0; mi < 2; ++mi)
#pragma unroll
        for (int ni = 0; ni < 2; ++ni)
          acc[mi][ni] = __builtin_amdgcn_mfma_f32_16x16x32_bf16(av[mi], bv[ni], acc[mi][ni], 0, 0, 0);
    }
    __syncthreads();
    cur ^= 1;
  }

  // epilogue: C/D layout col = lane&15 (n), row = 4*(lane>>4)+r (m)
  const float* bias = a.bia[gate];
  const int rg = lane >> 4;
  const int ci = lane & 15;
#pragma unroll
  for (int mi = 0; mi < 2; ++mi) {
#pragma unroll
    for (int ni = 0; ni < 2; ++ni) {
      const int col = n0 + wc2 * 32 + ni * 16 + ci;
      const float bvl = bias[col];
#pragma unroll
      for (int r = 0; r < 4; ++r) {
        const int row = m0 + wr * 32 + mi * 16 + rg * 4 + r;
        const float v = acc[mi][ni][r] + bvl;
        const size_t o = (size_t)row * 512 + col;
        if (gate == 0)      a.gdst[0][o] = f2bf(1.f / (1.f + __expf(-v)));
        else if (gate == 1) a.gdst[1][o] = f2bf(1.f / (1.f + __expf(-v)));
        else if (gate == 2) a.gdst[2][o] = f2bf(1.f - 2.f / (1.f + __expf(2.f * v)));
        else if (gate == 3) a.memo[o] = 0.5f / (1.f + __expf(-v));
        else                a.out0[o] = v;
      }
    }
  }
}

// Fused cumprod filter + cell shift + cell_new + hidden_new (+ bf16 hidden copy).
// WIDENED: 8 floats/thread as two f32x4 at idx and idx+1024 (each load/store
// instruction stays perfectly 1KB-per-wave coalesced). 1024 blocks; (256,4)
// -> ~60 VGPR, 16 waves/CU, >=4 outstanding 16B loads/lane = 32KB/CU in
// flight (need ~9KB for full HBM BW). Nontemporal single-use streams.
__global__ __launch_bounds__(256, 4) void cell_update_w(
    const float* __restrict__ cell, const short* __restrict__ igb,
    const short* __restrict__ ogb, const short* __restrict__ cgb,
    const float* __restrict__ mem, float* __restrict__ upd,
    float* __restrict__ hid, short* __restrict__ hidb)
{
  const size_t i0 = (size_t)blockIdx.x * 2048 + (size_t)threadIdx.x * 4;
  const size_t i1 = i0 + 1024;
  const f32x4 dv0 = *(const f32x4*)(mem + i0);
  const f32x4 dv1 = *(const f32x4*)(mem + i1);
  float d[8], p[8], acc[8];
#pragma unroll
  for (int j = 0; j < 4; ++j) {
    d[j] = dv0[j]; d[4 + j] = dv1[j];
    p[j] = 1.f; p[4 + j] = 1.f;
    acc[j] = 0.f; acc[4 + j] = 0.f;
  }
#pragma unroll
  for (int i = 0; i < 32; ++i) {
    const int k = 31 - i;
    const f32x4 c0 = ntload(cell + (size_t)k * BH + i0);
    const f32x4 c1 = ntload(cell + (size_t)k * BH + i1);
    const float inv = 1.f / (float)(i + 1);
#pragma unroll
    for (int j = 0; j < 4; ++j) {
      p[j] *= ((float)i - d[j]) * inv;          // cumprod factor (i - d)/(i+1)
      acc[j] += c0[j] * p[j];
      p[4 + j] *= ((float)i - d[4 + j]) * inv;
      acc[4 + j] += c1[j] * p[4 + j];
    }
    if (k >= 1) {
      ntstore(upd + (size_t)(k - 1) * BH + i0, c0);   // shift copy
      ntstore(upd + (size_t)(k - 1) * BH + i1, c1);
    }
  }
  const sh4 iv0 = *(const sh4*)(igb + i0), iv1 = *(const sh4*)(igb + i1);
  const sh4 ov0 = *(const sh4*)(ogb + i0), ov1 = *(const sh4*)(ogb + i1);
  const sh4 gv0 = *(const sh4*)(cgb + i0), gv1 = *(const sh4*)(cgb + i1);
  f32x4 cno0, cno1, ho0, ho1; sh4 hb0, hb1;
#pragma unroll
  for (int j = 0; j < 4; ++j) {
    const float cn0 = -acc[j] + bf2f(gv0[j]) * bf2f(iv0[j]);
    cno0[j] = cn0;
    const float th0 = 1.f - 2.f / (1.f + __expf(2.f * cn0));  // tanh, safe
    const float h0 = bf2f(ov0[j]) * th0;
    ho0[j] = h0; hb0[j] = f2bf(h0);
    const float cn1 = -acc[4 + j] + bf2f(gv1[j]) * bf2f(iv1[j]);
    cno1[j] = cn1;
    const float th1 = 1.f - 2.f / (1.f + __expf(2.f * cn1));
    const float h1 = bf2f(ov1[j]) * th1;
    ho1[j] = h1; hb1[j] = f2bf(h1);
  }
  ntstore(upd + (size_t)31 * BH + i0, cno0);
  ntstore(upd + (size_t)31 * BH + i1, cno1);
  *(f32x4*)(hid + i0) = ho0;
  *(f32x4*)(hid + i1) = ho1;
  *(sh4*)(hidb + i0) = hb0;
  *(sh4*)(hidb + i1) = hb1;
}

// ============================ FALLBACK (round-3, passed) ============================

struct GemmArgs {
  const float *sample, *hidden, *memp, *hid_in;
  const float *W[5];
  const float *bia[5];
  float *dst[5];
};

__global__ __launch_bounds__(256) void gemm_all(GemmArgs g, int mode) {
  __shared__ short lA[128 * 64];
  __shared__ short lB[128 * 64];
  const int t = threadIdx.x;
  const int lane = t & 63;
  const int mt = blockIdx.x;
  int gate, nsub;
  if (mode == 0) { gate = blockIdx.y >> 2; nsub = blockIdx.y & 3; }
  else           { gate = 4;               nsub = blockIdx.y; }
  const float* W = g.W[gate];
  const float* bias = g.bia[gate];
  float* dst = g.dst[gate];
  const int Klen = (gate == 3) ? 1536 : (gate == 4 ? 512 : 1024);
  const int m0 = mt * 128;
  const int n0 = nsub * 128;

  f32x4 acc[4][4];
  const f32x4 z = {0.f, 0.f, 0.f, 0.f};
#pragma unroll
  for (int i = 0; i < 4; ++i)
#pragma unroll
    for (int j = 0; j < 4; ++j) acc[i][j] = z;

  const int wv = t >> 6;
  const int wr = wv >> 1, wc = wv & 1;
  const int Ktiles = Klen >> 6;
  for (int kt = 0; kt < Ktiles; ++kt) {
    const int kb = kt << 6;
#pragma unroll
    for (int it = 0; it < 4; ++it) {
      const int chunk = it * 256 + t;
      const int row = chunk >> 3;
      const int kk = (chunk & 7) << 3;
      const int gk = kb + kk;
      const float* src;
      if (mode == 1)      src = g.hid_in + (size_t)(m0 + row) * 512 + gk;
      else if (gk < 512)  src = g.sample + (size_t)(m0 + row) * 512 + gk;
      else if (gk < 1024) src = g.hidden + (size_t)(m0 + row) * 512 + (gk - 512);
      else                src = g.memp   + (size_t)(m0 + row) * 512 + (gk - 1024);
      const f32x4 v0 = *(const f32x4*)src;
      const f32x4 v1 = *(const f32x4*)(src + 4);
      short8 s;
#pragma unroll
      for (int j = 0; j < 4; ++j) { s[j] = f2bf(v0[j]); s[4 + j] = f2bf(v1[j]); }
      *(short8*)(lA + row * 64 + kk) = s;
    }
#pragma unroll
    for (int it = 0; it < 4; ++it) {
      const int chunk = it * 256 + t;
      const int row = chunk >> 3;
      const int kk = (chunk & 7) << 3;
      const float* src = W + (size_t)(n0 + row) * Klen + kb + kk;
      const f32x4 v0 = *(const f32x4*)src;
      const f32x4 v1 = *(const f32x4*)(src + 4);
      short8 s;
#pragma unroll
      for (int j = 0; j < 4; ++j) { s[j] = f2bf(v0[j]); s[4 + j] = f2bf(v1[j]); }
      *(short8*)(lB + row * 64 + kk) = s;
    }
    __syncthreads();
#pragma unroll
    for (int ks = 0; ks < 2; ++ks) {
      short8 av[4], bv[4];
#pragma unroll
      for (int mi = 0; mi < 4; ++mi)
        av[mi] = *(const short8*)(lA + (wr * 64 + mi * 16 + (lane & 15)) * 64 + ks * 32 + ((lane >> 4) << 3));
#pragma unroll
      for (int ni = 0; ni < 4; ++ni)
        bv[ni] = *(const short8*)(lB + (wc * 64 + ni * 16 + (lane & 15)) * 64 + ks * 32 + ((lane >> 4) << 3));
#pragma unroll
      for (int mi = 0; mi < 4; ++mi)
#pragma unroll
        for (int ni = 0; ni < 4; ++ni)
          acc[mi][ni] = __builtin_amdgcn_mfma_f32_16x16x32_bf16(av[mi], bv[ni], acc[mi][ni], 0, 0, 0);
    }
    __syncthreads();
  }

  const int rg = lane >> 4;
  const int ci = lane & 15;
#pragma unroll
  for (int mi = 0; mi < 4; ++mi) {
#pragma unroll
    for (int ni = 0; ni < 4; ++ni) {
      const int col = n0 + wc * 64 + ni * 16 + ci;
      const float bvl = bias[col];
#pragma unroll
      for (int r = 0; r < 4; ++r) {
        const int row = m0 + wr * 64 + mi * 16 + rg * 4 + r;
        const float v = acc[mi][ni][r] + bvl;
        float o;
        if (gate == 0 || gate == 1)  o = 1.f / (1.f + __expf(-v));
        else if (gate == 2)          o = 1.f - 2.f / (1.f + __expf(2.f * v));
        else if (gate == 3)          o = 0.5f / (1.f + __expf(-v));
        else                         o = v;
        dst[(size_t)row * 512 + col] = o;
      }
    }
  }
}

__global__ __launch_bounds__(256) void cell_update(
    const float* __restrict__ cell, const float* ig, const float* og, const float* cg,
    const float* mem, float* upd, float* __restrict__ hid)
{
  const size_t idx = ((size_t)blockIdx.x * 256 + threadIdx.x) * 4;
  const f32x4 dv = *(const f32x4*)(mem + idx);
  const f32x4 iv = *(const f32x4*)(ig + idx);
  const f32x4 ov = *(const f32x4*)(og + idx);
  const f32x4 gv = *(const f32x4*)(cg + idx);
  asm volatile("" ::: "memory");
  float p[4], acc[4];
#pragma unroll
  for (int j = 0; j < 4; ++j) { p[j] = 1.f; acc[j] = 0.f; }
#pragma unroll
  for (int i = 0; i < 32; ++i) {
    const int k = 31 - i;
    const f32x4 c = *(const f32x4*)(cell + (size_t)k * BH + idx);
    const float inv = 1.f / (float)(i + 1);
#pragma unroll
    for (int j = 0; j < 4; ++j) {
      p[j] *= ((float)i - dv[j]) * inv;
      acc[j] += c[j] * p[j];
    }
    if (k >= 1) *(f32x4*)(upd + (size_t)(k - 1) * BH + idx) = c;
  }
  f32x4 cno, ho;
#pragma unroll
  for (int j = 0; j < 4; ++j) {
    const float cn = -acc[j] + gv[j] * iv[j];
    cno[j] = cn;
    const float th = 1.f - 2.f / (1.f + __expf(2.f * cn));
    ho[j] = ov[j] * th;
  }
  *(f32x4*)(upd + (size_t)31 * BH + idx) = cno;
  *(f32x4*)(hid + idx) = ho;
}

// ============================ launch ============================

extern "C" void kernel_launch(void* const* d_in, const int* in_sizes, int n_in,
                              void* d_out, int out_size, void* d_ws, size_t ws_size,
                              hipStream_t stream) {
  const float* sample = (const float*)d_in[0];
  const float* hidden = (const float*)d_in[1];
  const float* cell   = (const float*)d_in[2];
  const float* memp   = (const float*)d_in[3];

  float* out0 = (float*)d_out;                 // [B,O]   output
  float* hid  = out0 + (size_t)BH;             // [B,H]   hidden_new
  float* upd  = hid + (size_t)BH;              // [K,B,H] updated_cell_states
  float* memo = upd + (size_t)NK * BH;         // [B,H]   mem_new

  if (ws_size >= FAST_NEED_BYTES) {
    short* ws = (short*)d_ws;
    hipLaunchKernelGGL(prep, dim3(8704), dim3(256), 0, stream,
                       sample, hidden, memp,
                       (const float*)d_in[4], (const float*)d_in[6],
                       (const float*)d_in[10], (const float*)d_in[8],
                       (const float*)d_in[12], ws);
    FastArgs a;
    a.xh = ws + WS_XH; a.mempb = ws + WS_MEMPB; a.hidb = ws + WS_HIDB;
    a.W[0] = ws + WS_WI; a.W[1] = ws + WS_WO; a.W[2] = ws + WS_WC;
    a.W[3] = ws + WS_WM; a.W[4] = ws + WS_WOUT;
    a.bia[0] = (const float*)d_in[5];  a.bia[1] = (const float*)d_in[7];
    a.bia[2] = (const float*)d_in[11]; a.bia[3] = (const float*)d_in[9];
    a.bia[4] = (const float*)d_in[13];
    a.gdst[0] = ws + WS_IGB; a.gdst[1] = ws + WS_OGB; a.gdst[2] = ws + WS_CGB;
    a.memo = memo; a.out0 = out0;

    hipLaunchKernelGGL(gemm_fast, dim3(64, 32), dim3(256), 0, stream, a, 0);
    hipLaunchKernelGGL(cell_update_w, dim3(1024), dim3(256), 0, stream,
                       cell, (const short*)a.gdst[0], (const short*)a.gdst[1],
                       (const short*)a.gdst[2], (const float*)memo, upd, hid,
                       ws + WS_HIDB);
    hipLaunchKernelGGL(gemm_fast, dim3(64, 8), dim3(256), 0, stream, a, 1);
    return;
  }

  // fallback: round-3 path (passed)
  float* ig;
  float* og;
  float* cg;
  if (ws_size >= (size_t)3 * BH * sizeof(float)) {
    ig = (float*)d_ws; og = ig + (size_t)BH; cg = og + (size_t)BH;
  } else {
    ig = upd; og = upd + (size_t)BH; cg = upd + 2 * (size_t)BH;
  }
  GemmArgs g;
  g.sample = sample; g.hidden = hidden; g.memp = memp; g.hid_in = hid;
  g.W[0] = (const float*)d_in[4];  g.bia[0] = (const float*)d_in[5];
  g.W[1] = (const float*)d_in[6];  g.bia[1] = (const float*)d_in[7];
  g.W[3] = (const float*)d_in[8];  g.bia[3] = (const float*)d_in[9];
  g.W[2] = (const float*)d_in[10]; g.bia[2] = (const float*)d_in[11];
  g.W[4] = (const float*)d_in[12]; g.bia[4] = (const float*)d_in[13];
  g.dst[0] = ig; g.dst[1] = og; g.dst[2] = cg; g.dst[3] = memo; g.dst[4] = out0;

  hipLaunchKernelGGL(gemm_all, dim3(32, 16), dim3(256), 0, stream, g, 0);
  hipLaunchKernelGGL(cell_update, dim3(2048), dim3(256), 0, stream,
                     cell, (const float*)ig, (const float*)og, (const float*)cg,
                     (const float*)memo, upd, hid);
  hipLaunchKernelGGL(gemm_all, dim3(32, 4), dim3(256), 0, stream, g, 1);
}